// Round 11
// baseline (221.043 us; speedup 1.0000x reference)
//
#include <hip/hip_runtime.h>
#include <math.h>

#define BB 32
#define NN 1024
#define DD 128

typedef __bf16 bf16;
typedef bf16 bf16x4 __attribute__((ext_vector_type(4)));
typedef bf16 bf16x8 __attribute__((ext_vector_type(8)));
typedef float f32x4 __attribute__((ext_vector_type(4)));

#define MFMA16(a, b, c) __builtin_amdgcn_mfma_f32_16x16x32_bf16(a, b, c, 0, 0, 0)

// ---------------- K0: fused prep + weight transpose ----------------
// blocks 0..1023: Xbf=bf16(P); Pq=bf16(P*wc); Ptp[b][d][n]=bf16(P[b][n][d]);
//                 t[b][n]=P_n.wa  (wb dead: constant over softmax axis)
// blocks 1024..1119: WtG[mat*128+col][k] = bf16(w_mat[k][col])
#define LTS 133
__global__ __launch_bounds__(256) void k_prep(const float* __restrict__ P,
                                              const float* __restrict__ w_itr,
                                              const float* __restrict__ w1,
                                              const float* __restrict__ w2,
                                              const float* __restrict__ w3,
                                              bf16* __restrict__ Xbf,
                                              bf16* __restrict__ Pq,
                                              bf16* __restrict__ Ptp,
                                              float* __restrict__ t,
                                              bf16* __restrict__ WtG) {
    __shared__ __align__(16) float Lt[32 * LTS];
    int tid = threadIdx.x;
    if (blockIdx.x >= 1024) {
        // ---- weight transpose path ----
        float (*Lw)[33] = (float(*)[33])Lt;
        int bi = blockIdx.x - 1024;          // 0..95 = 3 mats * 8 kt * 4 ct
        int mat = bi >> 5, rem = bi & 31;
        int kt = rem >> 2, ct = rem & 3;
        const float* wsrc = (mat == 0) ? w1 : ((mat == 1) ? w2 : w3);
#pragma unroll
        for (int p = 0; p < 4; ++p) {
            int idx = tid + p * 256;
            Lw[idx >> 5][idx & 31] = wsrc[(kt * 32 + (idx >> 5)) * DD + ct * 32 + (idx & 31)];
        }
        __syncthreads();
        int colg = tid >> 3, kq = tid & 7;
        bf16x4 v;
#pragma unroll
        for (int e = 0; e < 4; ++e) v[e] = (bf16)Lw[kq * 4 + e][colg];
        *(bf16x4*)&WtG[(mat * 128 + ct * 32 + colg) * 256 + kt * 32 + kq * 4] = v;
        return;
    }
    // ---- prep path: 32 rows/block; Xbf/Pq/t straight from registers ----
    int b = blockIdx.x >> 5, g = blockIdx.x & 31;
    int n0 = g * 32;
    int row = tid >> 3, q8 = tid & 7, d0 = q8 * 16;
    long rowg = (long)b * NN + n0 + row;
    float r[16];
#pragma unroll
    for (int i = 0; i < 4; ++i) {
        float4 v = *(const float4*)&P[rowg * DD + d0 + 4 * i];
        r[4 * i + 0] = v.x; r[4 * i + 1] = v.y; r[4 * i + 2] = v.z; r[4 * i + 3] = v.w;
        *(float4*)&Lt[row * LTS + d0 + 4 * i] = v;
    }
    {   // t = P . wa
        float wa[16];
#pragma unroll
        for (int i = 0; i < 4; ++i) {
            float4 wv = *(const float4*)&w_itr[d0 + 4 * i];
            wa[4 * i + 0] = wv.x; wa[4 * i + 1] = wv.y;
            wa[4 * i + 2] = wv.z; wa[4 * i + 3] = wv.w;
        }
        float s = 0.f;
#pragma unroll
        for (int k = 0; k < 16; ++k) s += r[k] * wa[k];
        s += __shfl_xor(s, 1); s += __shfl_xor(s, 2); s += __shfl_xor(s, 4);
        if (q8 == 0) t[rowg] = s;
    }
    {
        const float* wc = w_itr + 2 * DD;
        float wcr[16];
#pragma unroll
        for (int i = 0; i < 4; ++i) {
            float4 wv = *(const float4*)&wc[d0 + 4 * i];
            wcr[4 * i + 0] = wv.x; wcr[4 * i + 1] = wv.y;
            wcr[4 * i + 2] = wv.z; wcr[4 * i + 3] = wv.w;
        }
#pragma unroll
        for (int h = 0; h < 2; ++h) {
            bf16x8 xv, qv;
#pragma unroll
            for (int e = 0; e < 8; ++e) {
                float f = r[8 * h + e];
                xv[e] = (bf16)f;
                qv[e] = (bf16)(f * wcr[8 * h + e]);
            }
            *(bf16x8*)&Xbf[rowg * DD + d0 + 8 * h] = xv;
            *(bf16x8*)&Pq[rowg * DD + d0 + 8 * h] = qv;
        }
    }
    __syncthreads();
#pragma unroll
    for (int i = 0; i < 2; ++i) {
        int idx = tid + i * 256;            // 0..511: d = idx>>2, c = idx&3
        int d = idx >> 2, c = idx & 3;
        bf16x8 v;
#pragma unroll
        for (int e = 0; e < 8; ++e) v[e] = (bf16)Lt[(c * 8 + e) * LTS + d];
        *(bf16x8*)&Ptp[((long)b * DD + d) * NN + n0 + c * 8] = v;
    }
}

// ---------------- K1: fused attention + gated MLP (MFMA16, 16-q waves) ------
// Block = 4 waves = 2 q-subtiles (16 rows) x 2 key-halves (512 keys); grid 1024.
// Per-wave state halved vs MFMA32 version: O^T = 8 x f32x4 (32 AGPR), so
// total VGPR+AGPR ~140 -> 3 waves/SIMD (the R7/R10 plateau was 2/SIMD because
// AGPRs count against the unified file on top of the reported VGPR_Count).
// S^T = K*Q^T via MFMA16 (A=K-frag, B=Q-frag); P=exp(S+t) (no-max streaming
// softmax, logits tiny); C->B-layout transform for P via 3 shfl_xor(16/32/48);
// O^T = V^T*P, one MFMA16 (K=32) per 16-d tile. No K ping-pong (R10: hurt).
__global__ __launch_bounds__(256, 3) void k_attn(const bf16* __restrict__ Xbf,
                                                 const bf16* __restrict__ Pq,
                                                 const bf16* __restrict__ Ptp,
                                                 const float* __restrict__ t,
                                                 const bf16* __restrict__ WtG,
                                                 const float* __restrict__ b1,
                                                 const float* __restrict__ b2,
                                                 const float* __restrict__ b3,
                                                 float* __restrict__ out) {
    __shared__ __align__(16) char smem[35840];
    float* PA   = (float*)smem;              // merge: [2][16][132] f32 (16896 B)
    bf16*  Wst  = (bf16*)smem;               // alias tail: [128][72] bf16 (18432 B)
    float* ost  = (float*)smem;              // alias out-stage: [32][132] f32 (16896 B)
    bf16*  Xsh  = (bf16*)(smem + 18432);     // [32][264] bf16 (16896 B)
    float* lbuf = (float*)(smem + 35328);    // [2][32] f32

    const int tid = threadIdx.x;
    const int w = tid >> 6, lane = tid & 63;
    const int ln = lane & 15, qd = lane >> 4;      // col / quad
    const int qsub = w & 1, kh = w >> 1;
    const int b = blockIdx.x & 31, qt = blockIdx.x >> 5;
    const long qrow0 = (long)b * NN + qt * 32;
    const long kvrow = (long)b * NN;
    const long myq = qrow0 + qsub * 16;

    // Q B-fragments: B[k=d][n=q]: n=ln, d = c*32 + qd*8 + e
    bf16x8 Qb[4];
#pragma unroll
    for (int c = 0; c < 4; ++c)
        Qb[c] = *(const bf16x8*)&Pq[(myq + ln) * DD + c * 32 + qd * 8];

    f32x4 O[8];
#pragma unroll
    for (int dt = 0; dt < 8; ++dt) O[dt] = (f32x4){0.f, 0.f, 0.f, 0.f};
    float lsum = 0.f;

    for (int it = 0; it < 16; ++it) {
        const int j0 = kh * 512 + it * 32;
        // K A-fragments: A[m=key][k=d]: m=ln, d = c*32 + qd*8 (+e); 2 key-tiles
        bf16x8 kf0[4], kf1[4];
#pragma unroll
        for (int c = 0; c < 4; ++c) {
            kf0[c] = *(const bf16x8*)&Xbf[(kvrow + j0 + ln) * DD + c * 32 + qd * 8];
            kf1[c] = *(const bf16x8*)&Xbf[(kvrow + j0 + 16 + ln) * DD + c * 32 + qd * 8];
        }
        // V^T A-fragments: A[m=d][k=key]: m = dt*16+ln, keys = qd*8 (+e)
        bf16x8 vf[8];
#pragma unroll
        for (int dt = 0; dt < 8; ++dt)
            vf[dt] = *(const bf16x8*)&Ptp[((long)b * DD + dt * 16 + ln) * NN + j0 + qd * 8];
        // key bias (per C-row = key = tile*16 + qd*4 + r)
        float4 tv0 = *(const float4*)&t[kvrow + j0 + 4 * qd];
        float4 tv1 = *(const float4*)&t[kvrow + j0 + 16 + 4 * qd];

        f32x4 S0 = (f32x4){0.f, 0.f, 0.f, 0.f}, S1 = S0;
#pragma unroll
        for (int c = 0; c < 4; ++c) S0 = MFMA16(kf0[c], Qb[c], S0);
#pragma unroll
        for (int c = 0; c < 4; ++c) S1 = MFMA16(kf1[c], Qb[c], S1);

        float t0s[4] = {tv0.x, tv0.y, tv0.z, tv0.w};
        float t1s[4] = {tv1.x, tv1.y, tv1.z, tv1.w};
        bf16x4 a4, c4;
#pragma unroll
        for (int r = 0; r < 4; ++r) {
            float e0 = __expf(S0[r] + t0s[r]);
            float e1 = __expf(S1[r] + t1s[r]);
            lsum += e0 + e1;
            a4[r] = (bf16)e0;
            c4[r] = (bf16)e1;
        }
        // C-layout (lane holds keys tile*16+qd*4+r for q=ln) -> B-layout
        // (lane needs keys qd*8+e for q=ln): 3 selective half-wave swaps.
        union { bf16x4 h; int i[2]; } ua, ub, s16, s32, s48, r16, r32, r48;
        ua.h = a4; ub.h = c4;
        s16.i[0] = (qd < 2) ? ua.i[0] : ub.i[0];
        s16.i[1] = (qd < 2) ? ua.i[1] : ub.i[1];
        r16.i[0] = __shfl_xor(s16.i[0], 16, 64);
        r16.i[1] = __shfl_xor(s16.i[1], 16, 64);
        s32.i[0] = (qd & 1) ? ua.i[0] : ub.i[0];
        s32.i[1] = (qd & 1) ? ua.i[1] : ub.i[1];
        r32.i[0] = __shfl_xor(s32.i[0], 32, 64);
        r32.i[1] = __shfl_xor(s32.i[1], 32, 64);
        s48.i[0] = (qd == 2) ? ua.i[0] : ub.i[0];
        s48.i[1] = (qd == 2) ? ua.i[1] : ub.i[1];
        r48.i[0] = __shfl_xor(s48.i[0], 48, 64);
        r48.i[1] = __shfl_xor(s48.i[1], 48, 64);
        union { bf16x8 h; int i[4]; } Bp;
        int lo0 = (qd == 0) ? ua.i[0] : (qd == 1) ? r48.i[0] : (qd == 2) ? r32.i[0] : r16.i[0];
        int lo1 = (qd == 0) ? ua.i[1] : (qd == 1) ? r48.i[1] : (qd == 2) ? r32.i[1] : r16.i[1];
        int hi0 = (qd == 0) ? r16.i[0] : (qd == 1) ? r32.i[0] : (qd == 2) ? r48.i[0] : ub.i[0];
        int hi1 = (qd == 0) ? r16.i[1] : (qd == 1) ? r32.i[1] : (qd == 2) ? r48.i[1] : ub.i[1];
        Bp.i[0] = lo0; Bp.i[1] = lo1; Bp.i[2] = hi0; Bp.i[3] = hi1;
#pragma unroll
        for (int dt = 0; dt < 8; ++dt) O[dt] = MFMA16(vf[dt], Bp.h, O[dt]);
    }

    // ---- merge the 2 key-halves; build Xsh = [P | attn] (bf16) ----
    lsum += __shfl_xor(lsum, 16, 64);
    lsum += __shfl_xor(lsum, 32, 64);
    if (lane < 16) lbuf[kh * 32 + qsub * 16 + ln] = lsum;
    if (kh == 1) {
#pragma unroll
        for (int dt = 0; dt < 8; ++dt)
            *(f32x4*)&PA[(qsub * 16 + ln) * 132 + dt * 16 + qd * 4] = O[dt];
    }
    __syncthreads();
    if (kh == 0) {
        float ltot = lbuf[qsub * 16 + ln] + lbuf[32 + qsub * 16 + ln];
        float linv = 1.f / ltot;
#pragma unroll
        for (int dt = 0; dt < 8; ++dt) {
            f32x4 pa = *(const f32x4*)&PA[(qsub * 16 + ln) * 132 + dt * 16 + qd * 4];
            bf16x4 o4;
#pragma unroll
            for (int r = 0; r < 4; ++r) o4[r] = (bf16)((O[dt][r] + pa[r]) * linv);
            *(bf16x4*)&Xsh[(qsub * 16 + ln) * 264 + 128 + dt * 16 + qd * 4] = o4;
        }
    } else {
        // kh1 waves (tid 128..255): stage P-half of X coalesced from Xbf
        int tl = tid - 128;
#pragma unroll
        for (int i = 0; i < 4; ++i) {
            int idx = tl + i * 128;     // 0..511
            int row = idx >> 4, seg = idx & 15;
            *(bf16x8*)&Xsh[row * 264 + seg * 8] =
                *(const bf16x8*)&Xbf[(qrow0 + row) * DD + seg * 8];
        }
    }

    // ---- fused gated MLP on X=[P|attn]; W staged per (mat, 64-k phase) ----
    const int q3 = lane >> 4;
    const int rh = w & 1, ch = w >> 1;   // wave: rows rh*16.., cols ch*64..
    f32x4 gz[4], gr[4];
    float rres[16];
#pragma unroll
    for (int mat = 0; mat < 3; ++mat) {
        f32x4 acc[4];
#pragma unroll
        for (int nt = 0; nt < 4; ++nt) acc[nt] = (f32x4){0.f, 0.f, 0.f, 0.f};
#pragma unroll
        for (int k2 = 0; k2 < 4; ++k2) {
            __syncthreads();             // first one also protects Xsh build / PA death
#pragma unroll
            for (int i = 0; i < 4; ++i) {
                int idx = tid + i * 256;
                *(float4*)&Wst[(idx >> 3) * 72 + (idx & 7) * 8] =
                    *(const float4*)&WtG[(mat * 128 + (idx >> 3)) * 256 + k2 * 64 +
                                         (idx & 7) * 8];
            }
            __syncthreads();
#pragma unroll
            for (int kc2 = 0; kc2 < 2; ++kc2) {
                bf16x8 Af = *(const bf16x8*)&Xsh[(rh * 16 + ln) * 264 + k2 * 64 +
                                                 kc2 * 32 + q3 * 8];
#pragma unroll
                for (int nt = 0; nt < 4; ++nt) {
                    bf16x8 Bf = *(const bf16x8*)&Wst[(ch * 64 + nt * 16 + ln) * 72 +
                                                     kc2 * 32 + q3 * 8];
                    acc[nt] = MFMA16(Af, Bf, acc[nt]);
                }
            }
        }
        const float* bp = (mat == 0) ? b1 : ((mat == 1) ? b2 : b3);
#pragma unroll
        for (int nt = 0; nt < 4; ++nt) {
            int colc = ch * 64 + nt * 16 + ln;
            float bb = bp[colc];
#pragma unroll
            for (int r = 0; r < 4; ++r) {
                float y = acc[nt][r] + bb;
                if (mat == 0) gz[nt][r] = tanhf(y);
                else if (mat == 1) gr[nt][r] = 1.f / (1.f + __expf(-y));
                else {
                    float fg = 1.f / (1.f + __expf(-y));
                    int lrow = rh * 16 + q3 * 4 + r;
                    float p = (float)Xsh[lrow * 264 + colc];
                    rres[nt * 4 + r] = gr[nt][r] * p + fg * gz[nt][r];
                }
            }
        }
    }
    __syncthreads();                     // Wst dead -> out stage
#pragma unroll
    for (int nt = 0; nt < 4; ++nt)
#pragma unroll
        for (int r = 0; r < 4; ++r)
            ost[(rh * 16 + q3 * 4 + r) * 132 + ch * 64 + nt * 16 + ln] = rres[nt * 4 + r];
    __syncthreads();
#pragma unroll
    for (int i = 0; i < 4; ++i) {        // fully-coalesced float4 row stores
        int idx = tid + i * 256;         // 0..1023
        int row = idx >> 5, c4i = idx & 31;
        float4 v = *(const float4*)&ost[row * 132 + c4i * 4];
        *(float4*)&out[(qrow0 + row) * DD + c4i * 4] = v;
    }
}

extern "C" void kernel_launch(void* const* d_in, const int* in_sizes, int n_in,
                              void* d_out, int out_size, void* d_ws, size_t ws_size,
                              hipStream_t stream) {
    const float* P     = (const float*)d_in[0];
    const float* w_itr = (const float*)d_in[1];
    const float* w1    = (const float*)d_in[2];
    const float* w2    = (const float*)d_in[3];
    const float* w3    = (const float*)d_in[4];
    const float* b1    = (const float*)d_in[5];
    const float* b2    = (const float*)d_in[6];
    const float* b3    = (const float*)d_in[7];
    float* out = (float*)d_out;

    char* wsb = (char*)d_ws;
    bf16* Xbf  = (bf16*)(wsb);                    //  8,388,608 B
    bf16* Pq   = (bf16*)(wsb + 8388608);          //  8,388,608 B
    bf16* Ptp  = (bf16*)(wsb + 16777216);         //  8,388,608 B
    float* tws = (float*)(wsb + 25165824);        //    131,072 B
    bf16* WtG  = (bf16*)(wsb + 25296896);         //    196,608 B

    k_prep<<<dim3(1120), dim3(256), 0, stream>>>(P, w_itr, w1, w2, w3,
                                                 Xbf, Pq, Ptp, tws, WtG);
    k_attn<<<dim3(1024), dim3(256), 0, stream>>>(Xbf, Pq, Ptp, tws, WtG,
                                                 b1, b2, b3, out);
}